// Round 2
// baseline (2036.261 us; speedup 1.0000x reference)
//
#include <hip/hip_runtime.h>
#include <hip/hip_bf16.h>
#include <stdint.h>

// ---------------------------------------------------------------------------
// BasisCustBiLSTM: per-sample basis-mixed BiLSTM.
//   k_meta / k_xbf / k_whhp / k_bias / k_mixwih / k_gemm : prep (unchanged)
//   k_hinit: zeroes the h exchange buffers + flags through the MALL (sc0 sc1)
//     so k_recur can use monotone >= flag polling (re-launch safe via kernel
//     boundary).
//   k_recur R7: flags stay sc0sc1 (tiny, 8 trans/block/round, wave0-only
//     poll), but the 32 KB/step bulk h payload is read with NORMAL CACHED
//     loads after an agent-scope acquire fence (buffer_inv: invalidates
//     L1 + this XCD's L2). The 32 blocks of an XCD then share each h line
//     through L2 -> MALL transaction count for the broadcast drops ~16-32x
//     vs R6's sc0sc1 bulk (which re-fetched every line per reader).
//     R5/R6 evidence: exchange is MALL request-service + RT bound, not
//     byte-bandwidth bound.
//     Correctness: producer release = sc0sc1 h stores -> vmcnt(0) -> sc0sc1
//     flag store (visible-at-MALL order). Reader acquire = sc0sc1 flag poll
//     -> fence(acquire, agent) -> cached loads (stale L2/L1 lines
//     invalidated; fresh lines pulled from MALL). XCD-mapping independent.
//     Overwrite safety unchanged from R6 (transitive flag argument; cached
//     reads complete into registers before S3/publish, same as before).
//     Wave roles: w0 poll+cell, w1 cell, w2 out-store, w3 h publish.
// ---------------------------------------------------------------------------

typedef __attribute__((ext_vector_type(8))) __bf16 bf16x8;
typedef __attribute__((ext_vector_type(4))) __bf16 bf16x4;
typedef __attribute__((ext_vector_type(4))) float  f32x4;
typedef __attribute__((ext_vector_type(4))) unsigned u32x4;
typedef __attribute__((ext_vector_type(2))) unsigned u32x2;

#define TT 256
#define BBATCH 32

__device__ __forceinline__ __bf16 f2bf(float f){
  unsigned u = __builtin_bit_cast(unsigned, f);
  unsigned short r = (unsigned short)((u + 0x7fffu + ((u >> 16) & 1u)) >> 16);
  return __builtin_bit_cast(__bf16, r);
}
__device__ __forceinline__ float sigm(float x){
  x = fminf(fmaxf(x, -30.f), 30.f);
  return 1.f / (1.f + __expf(-x));
}
__device__ __forceinline__ float tanh_(float x){
  x = fminf(fmaxf(x, -15.f), 15.f);
  float e = __expf(2.f * x);
  return (e - 1.f) / (e + 1.f);
}

// --- coherent (MALL-level) access helpers: sc0 sc1 = bypass L1+L2 ----------
__device__ __forceinline__ u32x2 ld_b64_coh(const void* p){
  u32x2 v;
  asm volatile("global_load_dwordx2 %0, %1, off sc0 sc1"
               : "=v"(v) : "v"(p) : "memory");
  return v;
}
__device__ __forceinline__ void st_b128_coh(void* p, u32x4 v){
  asm volatile("global_store_dwordx4 %0, %1, off sc0 sc1"
               :: "v"(p), "v"(v) : "memory");
}
__device__ __forceinline__ void st_b64_coh(void* p, u32x2 v){
  asm volatile("global_store_dwordx2 %0, %1, off sc0 sc1"
               :: "v"(p), "v"(v) : "memory");
}
__device__ __forceinline__ void st_b32_coh(void* p, unsigned v){
  asm volatile("global_store_dword %0, %1, off sc0 sc1"
               :: "v"(p), "v"(v) : "memory");
}

// ---------------------------------------------------------------------------
__global__ void k_meta(const void* __restrict__ mask,
                       const int* __restrict__ meta_a, const int* __restrict__ meta_c,
                       const float* __restrict__ emb_a, const float* __restrict__ emb_c,
                       const float* __restrict__ W1, const float* __restrict__ b1,
                       const float* __restrict__ W2,
                       float* __restrict__ c_out, int* __restrict__ len_out)
{
  __shared__ int s_bad;
  __shared__ float q_sh[32][128];
  __shared__ float hid[32][64];
  const int tid = threadIdx.x;
  if (tid == 0) s_bad = 0;
  __syncthreads();

  if (tid < 32){
    const unsigned char* m8 = (const unsigned char*)mask;
    int cnt = 0, seen0 = 0, bad = 0;
    for (int t = 0; t < TT; ++t){
      unsigned char v = m8[tid * TT + t];
      if (v > 1) bad = 1;
      if (v){ if (seen0) bad = 1; cnt++; } else seen0 = 1;
    }
    if (tid == 0 && cnt != TT) bad = 1;
    if (bad) atomicAdd(&s_bad, 1);
    len_out[tid] = cnt;
  }
  {
    int b = tid >> 3, p = tid & 7;
    int a = meta_a[b], c = meta_c[b];
    for (int i = 0; i < 16; ++i){
      int qi = p * 16 + i;
      q_sh[b][qi] = (qi < 64) ? emb_a[a * 64 + qi] : emb_c[c * 64 + (qi - 64)];
    }
  }
  __syncthreads();
  if (s_bad){
    if (tid < 32){
      const int* m32 = (const int*)mask;
      int cnt = 0;
      for (int t = 0; t < TT; ++t) if (m32[tid * TT + t]) cnt++;
      len_out[tid] = cnt;
    }
  }
  {
    int b = tid >> 3, kg = tid & 7;
    for (int k8 = 0; k8 < 8; ++k8){
      int k = kg * 8 + k8;
      float s = b1[k];
      for (int i = 0; i < 128; ++i) s += q_sh[b][i] * W1[i * 64 + k];
      hid[b][k] = tanhf(s);
    }
  }
  __syncthreads();
  if (tid < 32){
    float lg[8]; float mx = -1e30f;
    for (int n = 0; n < 8; ++n){
      float s = 0.f;
      for (int k = 0; k < 64; ++k) s += hid[tid][k] * W2[k * 8 + n];
      lg[n] = s; mx = fmaxf(mx, s);
    }
    float den = 0.f;
    for (int n = 0; n < 8; ++n){ lg[n] = expf(lg[n] - mx); den += lg[n]; }
    for (int n = 0; n < 8; ++n) c_out[tid * 8 + n] = lg[n] / den;
  }
}

// ---------------------------------------------------------------------------
// zero the h exchange region (2 dir x 2 buf x 32 KB data + 1 KB flags)
// through the MALL so monotone >= flag polling is re-launch safe.
__global__ void k_hinit(u32x4* hx)
{
  int i = blockIdx.x * 256 + threadIdx.x;
  if (i >= 8256) return;            // 8256 * 16 B = 132096 B
  u32x4 z = {0u, 0u, 0u, 0u};
  st_b128_coh(hx + i, z);
  asm volatile("s_waitcnt vmcnt(0)" ::: "memory");
}

// ---------------------------------------------------------------------------
__global__ void k_xbf(const float* __restrict__ x, __bf16* __restrict__ xb)
{
  int i = blockIdx.x * 256 + threadIdx.x;
  if (i >= 524288) return;
  f32x4 a = *(const f32x4*)(x + (size_t)i * 8);
  f32x4 b = *(const f32x4*)(x + (size_t)i * 8 + 4);
  bf16x8 o;
  #pragma unroll
  for (int j = 0; j < 4; ++j){ o[j] = f2bf(a[j]); o[4 + j] = f2bf(b[j]); }
  *(bf16x8*)(xb + (size_t)i * 8) = o;
}

// ---------------------------------------------------------------------------
__global__ void k_whhp(const float* __restrict__ whh_f, const float* __restrict__ whh_r,
                       __bf16* __restrict__ outp)
{
  int idx = blockIdx.x * 256 + threadIdx.x;
  int lane = idx & 63; int grp = idx >> 6;
  int n  = grp & 7;  grp >>= 3;
  int kt = grp & 3;  grp >>= 2;
  int wv = grp & 3;  grp >>= 2;
  int wg = grp & 127; int dir = (grp >> 7) & 1;
  int col = lane & 15, quad = lane >> 4;
  int gate = col >> 2, jj = col & 3;
  int g = gate * 512 + wg * 4 + jj;
  int k = (wv * 4 + kt) * 32 + quad * 8;
  const float* Wb = dir ? whh_r : whh_f;
  const float* s = Wb + ((size_t)n * 2048 + g) * 512 + k;
  f32x4 a = *(const f32x4*)s, b = *(const f32x4*)(s + 4);
  bf16x8 o;
  #pragma unroll
  for (int j = 0; j < 4; ++j){ o[j] = f2bf(a[j]); o[4 + j] = f2bf(b[j]); }
  *(bf16x8*)(outp + (size_t)idx * 8) = o;
}

// ---------------------------------------------------------------------------
__global__ void k_bias(const float* __restrict__ b_f, const float* __restrict__ b_r,
                       const float* __restrict__ cb, float* __restrict__ bm)
{
  int idx = blockIdx.x * 256 + threadIdx.x;
  int dir = idx >> 16; int b = (idx >> 11) & 31; int g = idx & 2047;
  const float* bb = dir ? b_r : b_f;
  float s = 0.f;
  #pragma unroll
  for (int n = 0; n < 8; ++n) s += cb[b * 8 + n] * bb[n * 2048 + g];
  bm[idx] = s;
}

// ---------------------------------------------------------------------------
__global__ void k_mixwih(const float* __restrict__ Wb, const float* __restrict__ cb,
                         __bf16* __restrict__ wmix)
{
  __shared__ float cs[256];
  int tid = threadIdx.x;
  cs[tid] = cb[tid];
  __syncthreads();
  int idx = blockIdx.x * 256 + tid;
  int g = idx >> 6, k8 = idx & 63;
  float src[8][8];
  #pragma unroll
  for (int n = 0; n < 8; ++n){
    const float* p = Wb + ((size_t)n * 2048 + g) * 512 + k8 * 8;
    f32x4 lo = *(const f32x4*)p, hi = *(const f32x4*)(p + 4);
    #pragma unroll
    for (int j = 0; j < 4; ++j){ src[n][j] = lo[j]; src[n][4 + j] = hi[j]; }
  }
  for (int b = 0; b < 32; ++b){
    float acc[8] = {0,0,0,0,0,0,0,0};
    #pragma unroll
    for (int n = 0; n < 8; ++n){
      float cn = cs[b * 8 + n];
      #pragma unroll
      for (int j = 0; j < 8; ++j) acc[j] += cn * src[n][j];
    }
    bf16x8 o;
    #pragma unroll
    for (int j = 0; j < 8; ++j) o[j] = f2bf(acc[j]);
    *(bf16x8*)(wmix + ((size_t)b * 2048 + g) * 512 + k8 * 8) = o;
  }
}

// ---------------------------------------------------------------------------
__global__ __launch_bounds__(256) void k_gemm(const __bf16* __restrict__ xb,
                                              const __bf16* __restrict__ wmix,
                                              float* __restrict__ xp)
{
  __shared__ __bf16 As[128][72];
  __shared__ __bf16 Bs[128][72];
  const int tid = threadIdx.x, lane = tid & 63, wv = tid >> 6;
  const int quad = lane >> 4, c16 = lane & 15;
  const int wm_ = wv >> 1, wn_ = wv & 1;
  const int b = blockIdx.x >> 5, tile = blockIdx.x & 31;
  const int m0 = (tile >> 4) * 128, n0 = (tile & 15) * 128;
  const __bf16* Ap = xb + (size_t)b * TT * 512;
  const __bf16* Bp = wmix + (size_t)b * 2048 * 512;
  float* Cp = xp + (size_t)b * TT * 2048;

  f32x4 acc[4][4];
  #pragma unroll
  for (int i = 0; i < 4; ++i)
    #pragma unroll
    for (int j = 0; j < 4; ++j) acc[i][j] = (f32x4){0,0,0,0};

  for (int k0 = 0; k0 < 512; k0 += 64){
    __syncthreads();
    #pragma unroll
    for (int it = 0; it < 4; ++it){
      int r = it * 32 + (tid >> 3), c = (tid & 7) * 8;
      *(bf16x8*)&As[r][c] = *(const bf16x8*)(Ap + (size_t)(m0 + r) * 512 + k0 + c);
      *(bf16x8*)&Bs[r][c] = *(const bf16x8*)(Bp + (size_t)(n0 + r) * 512 + k0 + c);
    }
    __syncthreads();
    #pragma unroll
    for (int kt = 0; kt < 2; ++kt){
      bf16x8 af[4], bfr[4];
      #pragma unroll
      for (int i = 0; i < 4; ++i){
        af[i]  = *(const bf16x8*)&As[wm_ * 64 + i * 16 + c16][kt * 32 + quad * 8];
        bfr[i] = *(const bf16x8*)&Bs[wn_ * 64 + i * 16 + c16][kt * 32 + quad * 8];
      }
      #pragma unroll
      for (int i = 0; i < 4; ++i)
        #pragma unroll
        for (int j = 0; j < 4; ++j)
          acc[i][j] = __builtin_amdgcn_mfma_f32_16x16x32_bf16(af[i], bfr[j], acc[i][j], 0, 0, 0);
    }
  }
  #pragma unroll
  for (int i = 0; i < 4; ++i)
    #pragma unroll
    for (int j = 0; j < 4; ++j){
      int colg = n0 + wn_ * 64 + j * 16 + c16;
      #pragma unroll
      for (int r = 0; r < 4; ++r){
        int row = m0 + wm_ * 64 + i * 16 + quad * 4 + r;
        Cp[(size_t)row * 2048 + colg] = acc[i][j][r];
      }
    }
}

// ---------------------------------------------------------------------------
// k_recur R7.
//  hxch layout:
//    hdat[dir][buf][kb=0..63][sample=0..31][16 B]   4 x 32768 B @ offset 0
//      chunk (kb,sample) = h channels kb*8 .. kb*8+7 of sample, bf16.
//    hflag[dir][wg=0..127] u32                      1024 B     @ offset 131072
//      flag[wg] >= v  =>  wg's slice of h(v) is visible at the MALL in
//      buf[v&1] (for all v' <= v).
//  Producer (wave 3): sc0sc1-store 32 x 8 B h slices -> s_waitcnt vmcnt(0) ->
//    sc0sc1-store flag[wg] = t+1 (release through MALL).
//  Reader: wave 0 polls all 128 flags >= t via sc0sc1 (8 transactions/round,
//    coalesced), then __builtin_amdgcn_fence(ACQUIRE, "agent") (buffer_inv:
//    invalidates this CU's L1 + this XCD's L2 stale lines), __syncthreads,
//    then ALL waves bulk-load the 32 KB state with NORMAL CACHED loads ->
//    the ~32 blocks of an XCD share each line through L2; MALL sees ~1 fill
//    per line per XCD instead of one per reader.
//  Overwrite safety (unchanged): producer writes buf[t&1] with h(t+2) only
//  after its step-t+1 poll observed all flags >= t+1, which requires every
//  block to have completed its step-t reads of buf[t&1] (loads complete into
//  registers before S3; publish is after S3).
//  wg is XCD-swizzled (xproj/out 64B-line locality, kept from R4/R5).
// ---------------------------------------------------------------------------
__global__ __launch_bounds__(256, 1) void k_recur(
    const __bf16* __restrict__ whhp,
    const float*  __restrict__ xproj,   // [2][32][256][2048]
    const float*  __restrict__ biasm,   // [2][32][2048]
    const float*  __restrict__ cb,      // [32][8]
    const int*    __restrict__ lens,    // [32]
    void* hxch,                         // h exchange region (see above)
    float* __restrict__ out)            // [32][256][1024]
{
  const int tid = threadIdx.x, lane = tid & 63, wv = tid >> 6;
  const int quad = lane >> 4, c16 = lane & 15;
  const int bid = blockIdx.x, dir = bid >> 7;
  const int b7 = bid & 127;
  const int wg = ((b7 & 7) << 4) | (b7 >> 3);   // XCD-aware swizzle
  const int hidx0 = wg * 4;

  char* hd = (char*)hxch;
  const u32x4* hdat0 = (const u32x4*)(hd + (size_t)(dir * 2 + 0) * 32768);
  const u32x4* hdat1 = (const u32x4*)(hd + (size_t)(dir * 2 + 1) * 32768);
  unsigned* hflag = (unsigned*)(hd + 131072) + dir * 128;

  // basis-weight B fragments -> registers (logical-wg indexed)
  bf16x8 bfrag[4][8];
  {
    const __bf16* base = whhp + (size_t)((dir * 128 + wg) * 4 + wv) * 4 * (8 * 512);
    #pragma unroll
    for (int kt = 0; kt < 4; ++kt)
      #pragma unroll
      for (int n = 0; n < 8; ++n)
        bfrag[kt][n] = *(const bf16x8*)(base + (size_t)(kt * 8 + n) * 512 + lane * 8);
  }
  f32x4 ccv[2][8];
  #pragma unroll
  for (int mt = 0; mt < 2; ++mt)
    #pragma unroll
    for (int n = 0; n < 8; ++n){
      f32x4 v;
      #pragma unroll
      for (int r = 0; r < 4; ++r) v[r] = cb[(mt * 16 + quad * 4 + r) * 8 + n];
      ccv[mt][n] = v;
    }

  const int bb_ = tid >> 2, jj_ = tid & 3;
  float bias_g[4] = {0, 0, 0, 0};
  int mylen = 0;
  float cstate = 0.f;
  if (tid < 128){
    #pragma unroll
    for (int g = 0; g < 4; ++g)
      bias_g[g] = biasm[(size_t)(dir * 32 + bb_) * 2048 + g * 512 + hidx0 + jj_];
    mylen = lens[bb_];
  }

  __shared__ float red[4][2][64][4];
  __shared__ float xg[32][4][4];
  __shared__ float outst[32][4];
  __shared__ __bf16 hbst[32][4];

  // prefetch xproj for step 0 (normal cached load; waves 0-1)
  f32x4 pf = {0, 0, 0, 0};
  const int b_pf = tid >> 2, g_pf = tid & 3;
  if (tid < 128){
    int to0 = dir ? (TT - 1) : 0;
    pf = *(const f32x4*)(xproj + ((size_t)(dir * 32 + b_pf) * TT + to0) * 2048
                         + g_pf * 512 + hidx0);
  }

  // per-lane chunk indices of the 8 bulk-load chunks (p = mt*4 + kt):
  //   kb = (wv*4+kt)*4 + quad, sample = mt*16 + c16  ->  channels
  //   (wv*4+kt)*32 + quad*8 .. +8 (same fragment map as R5/R6)
  int hidx[8];
  #pragma unroll
  for (int mt = 0; mt < 2; ++mt)
    #pragma unroll
    for (int kt = 0; kt < 4; ++kt)
      hidx[mt * 4 + kt] = (((wv * 4 + kt) * 4 + quad) * 32) + mt * 16 + c16;

  // producer store offset (wave 3, lane s = tid-192): channels wg*4..+3 of
  // sample s live at chunk (wg>>1, s), byte (wg&1)*8 inside it.
  const int pub_off = (((wg >> 1) * 32 + (tid - 192)) << 4) + ((wg & 1) << 3);

  for (int t = 0; t < TT; ++t){
    const int to = dir ? (TT - 1 - t) : t;
    const u32x4* hb = (t & 1) ? hdat1 : hdat0;
    const unsigned tgt = (unsigned)t;

    // ---- wave 0: poll flags (sc0sc1) until all 128 wgs published h(t),
    //      then acquire-fence so cached reads below see fresh data ----
    if (wv == 0){
      const char* fp = (const char*)hflag + lane * 8;
      while (true){
        u32x2 f = ld_b64_coh(fp);
        asm volatile("s_waitcnt vmcnt(0)" : "+v"(f) :: "memory");
        if (__all((int)(f[0] >= tgt && f[1] >= tgt))) break;
      }
      __builtin_amdgcn_fence(__ATOMIC_ACQUIRE, "agent");
    }
    __syncthreads();     // S1: release all waves; L1/L2 stale lines invalidated

    // ---- bulk-load this wave's quarter of the h state (cached, once) ----
    u32x4 hv[8];
    #pragma unroll
    for (int p = 0; p < 8; ++p)
      hv[p] = hb[hidx[p]];
    bf16x8 af[2][4];
    #pragma unroll
    for (int p = 0; p < 8; ++p)
      af[p >> 2][p & 3] = __builtin_bit_cast(bf16x8, hv[p]);

    f32x4 acc[8][2];
    #pragma unroll
    for (int n = 0; n < 8; ++n){ acc[n][0] = (f32x4){0,0,0,0}; acc[n][1] = (f32x4){0,0,0,0}; }
    #pragma unroll
    for (int kt = 0; kt < 4; ++kt)
      #pragma unroll
      for (int n = 0; n < 8; ++n){
        acc[n][0] = __builtin_amdgcn_mfma_f32_16x16x32_bf16(af[0][kt], bfrag[kt][n], acc[n][0], 0, 0, 0);
        acc[n][1] = __builtin_amdgcn_mfma_f32_16x16x32_bf16(af[1][kt], bfrag[kt][n], acc[n][1], 0, 0, 0);
      }
    f32x4 mix0 = {0,0,0,0}, mix1 = {0,0,0,0};
    #pragma unroll
    for (int n = 0; n < 8; ++n){
      mix0 += ccv[0][n] * acc[n][0];
      mix1 += ccv[1][n] * acc[n][1];
    }
    *(f32x4*)&red[wv][0][lane][0] = mix0;
    *(f32x4*)&red[wv][1][lane][0] = mix1;
    if (tid < 128)
      *(f32x4*)&xg[b_pf][g_pf][0] = pf;
    __syncthreads();     // S2

    if (tid < 128){
      const int r = bb_ & 15, mt = bb_ >> 4, rg = r & 3, qp = r >> 2;
      float gv[4];
      #pragma unroll
      for (int g = 0; g < 4; ++g){
        int li = qp * 16 + g * 4 + jj_;
        float s = red[0][mt][li][rg] + red[1][mt][li][rg]
                + red[2][mt][li][rg] + red[3][mt][li][rg];
        gv[g] = s + xg[bb_][g][jj_] + bias_g[g];
      }
      float i_ = sigm(gv[0]);
      float f_ = sigm(gv[1]);
      float g_ = tanh_(gv[2]);
      float o_ = sigm(gv[3]);
      bool valid = (to < mylen);
      float cy = valid ? (f_ * cstate + i_ * g_) : 0.f;
      float hy = valid ? (o_ * tanh_(cy)) : 0.f;
      cstate = cy;
      outst[bb_][jj_] = hy;
      hbst[bb_][jj_] = f2bf(hy);
    }
    __syncthreads();     // S3

    // wave 3: publish h slices for step t+1 (sc0sc1), drain, raise flag
    if (tid >= 192 && tid < 224){
      int s = tid - 192;
      union { bf16x4 h; u32x2 d; } u;
      u.h = *(bf16x4*)&hbst[s][0];
      char* hn = (char*)((t & 1) ? hdat0 : hdat1);
      st_b64_coh(hn + pub_off, u.d);
      asm volatile("s_waitcnt vmcnt(0)" ::: "memory");
      if (s == 0) st_b32_coh(hflag + wg, (unsigned)(t + 1));
    }
    // waves 0-1: prefetch next xproj (cached); wave 2: out store
    if (t < TT - 1 && tid < 128){
      int ton = dir ? (TT - 2 - t) : (t + 1);
      pf = *(const f32x4*)(xproj + ((size_t)(dir * 32 + b_pf) * TT + ton) * 2048
                           + g_pf * 512 + hidx0);
    }
    if (tid >= 128 && tid < 160){
      int s = tid - 128;
      *(f32x4*)(out + ((size_t)s * TT + to) * 1024 + dir * 512 + hidx0)
          = *(f32x4*)&outst[s][0];
    }
  }
}

// ---------------------------------------------------------------------------
extern "C" void kernel_launch(void* const* d_in, const int* in_sizes, int n_in,
                              void* d_out, int out_size, void* d_ws, size_t ws_size,
                              hipStream_t stream)
{
  const float* x      = (const float*)d_in[0];
  const void*  mask   = d_in[1];
  const int*   meta_a = (const int*)d_in[2];
  const int*   meta_c = (const int*)d_in[3];
  const float* emb_a  = (const float*)d_in[4];
  const float* emb_c  = (const float*)d_in[5];
  const float* P_W1   = (const float*)d_in[6];
  const float* P_b1   = (const float*)d_in[7];
  const float* P_W2   = (const float*)d_in[8];
  const float* W_ih   = (const float*)d_in[9];
  const float* W_hh   = (const float*)d_in[10];
  const float* bias_f = (const float*)d_in[11];
  const float* W_ih_r = (const float*)d_in[12];
  const float* W_hh_r = (const float*)d_in[13];
  const float* bias_r = (const float*)d_in[14];
  float* out = (float*)d_out;
  char* ws = (char*)d_ws;

  constexpr size_t OFF_C     = 0;           //   1 KB  c_batch
  constexpr size_t OFF_LEN   = 1024;        //  128 B  lengths
  constexpr size_t OFF_BIAS  = 4096;        //  512 KB mixed biases
  constexpr size_t OFF_H     = 528384;      //  129 KB h data + flags
  constexpr size_t OFF_WHHP  = 790528;      // 33.5 MB basis Whh fragments
  constexpr size_t OFF_XBF   = 34344960;    //  8.4 MB x bf16
  constexpr size_t OFF_WIHM  = 42733568;    //   67 MB mixed Wih (per-dir reuse)
  constexpr size_t OFF_XPROJ = 109842432;   //  134 MB xproj f32 (both dirs)
  constexpr size_t WS_NEED   = 244060160;
  if (ws_size < WS_NEED) return;

  float*   c_b   = (float*)(ws + OFF_C);
  int*     lens  = (int*)(ws + OFF_LEN);
  float*   biasm = (float*)(ws + OFF_BIAS);
  void*    hxch  = (void*)(ws + OFF_H);
  __bf16*  whhp  = (__bf16*)(ws + OFF_WHHP);
  __bf16*  xbf   = (__bf16*)(ws + OFF_XBF);
  __bf16*  wihm  = (__bf16*)(ws + OFF_WIHM);
  float*   xproj = (float*)(ws + OFF_XPROJ);

  k_meta<<<1, 256, 0, stream>>>(mask, meta_a, meta_c, emb_a, emb_c,
                                P_W1, P_b1, P_W2, c_b, lens);
  k_hinit<<<33, 256, 0, stream>>>((u32x4*)hxch);
  k_xbf<<<2048, 256, 0, stream>>>(x, xbf);
  k_whhp<<<8192, 256, 0, stream>>>(W_hh, W_hh_r, whhp);
  k_bias<<<512, 256, 0, stream>>>(bias_f, bias_r, c_b, biasm);
  for (int dir = 0; dir < 2; ++dir){
    k_mixwih<<<512, 256, 0, stream>>>(dir ? W_ih_r : W_ih, c_b, wihm);
    k_gemm<<<1024, 256, 0, stream>>>(xbf, wihm,
                                     xproj + (size_t)dir * 32 * TT * 2048);
  }
  k_recur<<<256, 256, 0, stream>>>(whhp, xproj, biasm, c_b, lens, hxch, out);
}

// Round 3
// 1989.224 us; speedup vs baseline: 1.0236x; 1.0236x over previous
//
#include <hip/hip_runtime.h>
#include <hip/hip_bf16.h>
#include <stdint.h>

// ---------------------------------------------------------------------------
// BasisCustBiLSTM: per-sample basis-mixed BiLSTM.
//   k_meta / k_xbf / k_whhp / k_bias / k_mixwih / k_gemm : prep (unchanged)
//   k_cinit: zeroes the per-step publish counters through the MALL.
//   k_recur R8: write-once h journal.
//     R5-R7 lesson: the exchange is bound by serialized MALL round-trips and
//     by re-pulling sc0sc1 payload on every failed poll round; sc0sc1 payload
//     (R5/R6) or per-step buffer_inv (R7) were both losing moves. R8 removes
//     the staleness problem instead of fencing it: h(t) for each step goes to
//     a UNIQUE slot jrn[dir][t] (journal aliases the dead wihm region), so
//     journal lines are touched at most once per launch and plain CACHED
//     loads are always fresh (per-XCD L2 sharing for free, no fence).
//     Readiness: producers sc0sc1-store their 8B slices -> vmcnt(0) -> one
//     device-scope atomic_add on cnt[dir][t+1]. Readers: tid0 polls that
//     single word (==128), __syncthreads, then everyone bulk-loads cached.
//     Poll traffic: 256 single-lane loads/RT on 2 lines (vs R5's 262K
//     line-requests/round). Cross-launch freshness: dispatch-boundary L2
//     invalidation (already relied on for k_gemm->k_recur xproj) + one
//     agent-acquire fence at kernel entry.
//     Wave roles: w0 poll+cell, w1 cell, w2 out-store, w3 h publish.
// ---------------------------------------------------------------------------

typedef __attribute__((ext_vector_type(8))) __bf16 bf16x8;
typedef __attribute__((ext_vector_type(4))) __bf16 bf16x4;
typedef __attribute__((ext_vector_type(4))) float  f32x4;
typedef __attribute__((ext_vector_type(4))) unsigned u32x4;
typedef __attribute__((ext_vector_type(2))) unsigned u32x2;

#define TT 256
#define BBATCH 32

__device__ __forceinline__ __bf16 f2bf(float f){
  unsigned u = __builtin_bit_cast(unsigned, f);
  unsigned short r = (unsigned short)((u + 0x7fffu + ((u >> 16) & 1u)) >> 16);
  return __builtin_bit_cast(__bf16, r);
}
__device__ __forceinline__ float sigm(float x){
  x = fminf(fmaxf(x, -30.f), 30.f);
  return 1.f / (1.f + __expf(-x));
}
__device__ __forceinline__ float tanh_(float x){
  x = fminf(fmaxf(x, -15.f), 15.f);
  float e = __expf(2.f * x);
  return (e - 1.f) / (e + 1.f);
}

// --- coherent (MALL-level) store helpers: sc0 sc1 = bypass L1+L2 -----------
__device__ __forceinline__ void st_b64_coh(void* p, u32x2 v){
  asm volatile("global_store_dwordx2 %0, %1, off sc0 sc1"
               :: "v"(p), "v"(v) : "memory");
}
__device__ __forceinline__ void st_b32_coh(void* p, unsigned v){
  asm volatile("global_store_dword %0, %1, off sc0 sc1"
               :: "v"(p), "v"(v) : "memory");
}

// ---------------------------------------------------------------------------
__global__ void k_meta(const void* __restrict__ mask,
                       const int* __restrict__ meta_a, const int* __restrict__ meta_c,
                       const float* __restrict__ emb_a, const float* __restrict__ emb_c,
                       const float* __restrict__ W1, const float* __restrict__ b1,
                       const float* __restrict__ W2,
                       float* __restrict__ c_out, int* __restrict__ len_out)
{
  __shared__ int s_bad;
  __shared__ float q_sh[32][128];
  __shared__ float hid[32][64];
  const int tid = threadIdx.x;
  if (tid == 0) s_bad = 0;
  __syncthreads();

  if (tid < 32){
    const unsigned char* m8 = (const unsigned char*)mask;
    int cnt = 0, seen0 = 0, bad = 0;
    for (int t = 0; t < TT; ++t){
      unsigned char v = m8[tid * TT + t];
      if (v > 1) bad = 1;
      if (v){ if (seen0) bad = 1; cnt++; } else seen0 = 1;
    }
    if (tid == 0 && cnt != TT) bad = 1;
    if (bad) atomicAdd(&s_bad, 1);
    len_out[tid] = cnt;
  }
  {
    int b = tid >> 3, p = tid & 7;
    int a = meta_a[b], c = meta_c[b];
    for (int i = 0; i < 16; ++i){
      int qi = p * 16 + i;
      q_sh[b][qi] = (qi < 64) ? emb_a[a * 64 + qi] : emb_c[c * 64 + (qi - 64)];
    }
  }
  __syncthreads();
  if (s_bad){
    if (tid < 32){
      const int* m32 = (const int*)mask;
      int cnt = 0;
      for (int t = 0; t < TT; ++t) if (m32[tid * TT + t]) cnt++;
      len_out[tid] = cnt;
    }
  }
  {
    int b = tid >> 3, kg = tid & 7;
    for (int k8 = 0; k8 < 8; ++k8){
      int k = kg * 8 + k8;
      float s = b1[k];
      for (int i = 0; i < 128; ++i) s += q_sh[b][i] * W1[i * 64 + k];
      hid[b][k] = tanhf(s);
    }
  }
  __syncthreads();
  if (tid < 32){
    float lg[8]; float mx = -1e30f;
    for (int n = 0; n < 8; ++n){
      float s = 0.f;
      for (int k = 0; k < 64; ++k) s += hid[tid][k] * W2[k * 8 + n];
      lg[n] = s; mx = fmaxf(mx, s);
    }
    float den = 0.f;
    for (int n = 0; n < 8; ++n){ lg[n] = expf(lg[n] - mx); den += lg[n]; }
    for (int n = 0; n < 8; ++n) c_out[tid * 8 + n] = lg[n] / den;
  }
}

// ---------------------------------------------------------------------------
// zero the publish counters (2 dir x 256 steps x u32) through the MALL so
// k_recur's ==128 polling is re-launch safe (kernel-boundary ordering).
__global__ void k_cinit(unsigned* cnt)
{
  int i = blockIdx.x * 256 + threadIdx.x;
  if (i >= 512) return;
  st_b32_coh(cnt + i, 0u);
  asm volatile("s_waitcnt vmcnt(0)" ::: "memory");
}

// ---------------------------------------------------------------------------
__global__ void k_xbf(const float* __restrict__ x, __bf16* __restrict__ xb)
{
  int i = blockIdx.x * 256 + threadIdx.x;
  if (i >= 524288) return;
  f32x4 a = *(const f32x4*)(x + (size_t)i * 8);
  f32x4 b = *(const f32x4*)(x + (size_t)i * 8 + 4);
  bf16x8 o;
  #pragma unroll
  for (int j = 0; j < 4; ++j){ o[j] = f2bf(a[j]); o[4 + j] = f2bf(b[j]); }
  *(bf16x8*)(xb + (size_t)i * 8) = o;
}

// ---------------------------------------------------------------------------
__global__ void k_whhp(const float* __restrict__ whh_f, const float* __restrict__ whh_r,
                       __bf16* __restrict__ outp)
{
  int idx = blockIdx.x * 256 + threadIdx.x;
  int lane = idx & 63; int grp = idx >> 6;
  int n  = grp & 7;  grp >>= 3;
  int kt = grp & 3;  grp >>= 2;
  int wv = grp & 3;  grp >>= 2;
  int wg = grp & 127; int dir = (grp >> 7) & 1;
  int col = lane & 15, quad = lane >> 4;
  int gate = col >> 2, jj = col & 3;
  int g = gate * 512 + wg * 4 + jj;
  int k = (wv * 4 + kt) * 32 + quad * 8;
  const float* Wb = dir ? whh_r : whh_f;
  const float* s = Wb + ((size_t)n * 2048 + g) * 512 + k;
  f32x4 a = *(const f32x4*)s, b = *(const f32x4*)(s + 4);
  bf16x8 o;
  #pragma unroll
  for (int j = 0; j < 4; ++j){ o[j] = f2bf(a[j]); o[4 + j] = f2bf(b[j]); }
  *(bf16x8*)(outp + (size_t)idx * 8) = o;
}

// ---------------------------------------------------------------------------
__global__ void k_bias(const float* __restrict__ b_f, const float* __restrict__ b_r,
                       const float* __restrict__ cb, float* __restrict__ bm)
{
  int idx = blockIdx.x * 256 + threadIdx.x;
  int dir = idx >> 16; int b = (idx >> 11) & 31; int g = idx & 2047;
  const float* bb = dir ? b_r : b_f;
  float s = 0.f;
  #pragma unroll
  for (int n = 0; n < 8; ++n) s += cb[b * 8 + n] * bb[n * 2048 + g];
  bm[idx] = s;
}

// ---------------------------------------------------------------------------
__global__ void k_mixwih(const float* __restrict__ Wb, const float* __restrict__ cb,
                         __bf16* __restrict__ wmix)
{
  __shared__ float cs[256];
  int tid = threadIdx.x;
  cs[tid] = cb[tid];
  __syncthreads();
  int idx = blockIdx.x * 256 + tid;
  int g = idx >> 6, k8 = idx & 63;
  float src[8][8];
  #pragma unroll
  for (int n = 0; n < 8; ++n){
    const float* p = Wb + ((size_t)n * 2048 + g) * 512 + k8 * 8;
    f32x4 lo = *(const f32x4*)p, hi = *(const f32x4*)(p + 4);
    #pragma unroll
    for (int j = 0; j < 4; ++j){ src[n][j] = lo[j]; src[n][4 + j] = hi[j]; }
  }
  for (int b = 0; b < 32; ++b){
    float acc[8] = {0,0,0,0,0,0,0,0};
    #pragma unroll
    for (int n = 0; n < 8; ++n){
      float cn = cs[b * 8 + n];
      #pragma unroll
      for (int j = 0; j < 8; ++j) acc[j] += cn * src[n][j];
    }
    bf16x8 o;
    #pragma unroll
    for (int j = 0; j < 8; ++j) o[j] = f2bf(acc[j]);
    *(bf16x8*)(wmix + ((size_t)b * 2048 + g) * 512 + k8 * 8) = o;
  }
}

// ---------------------------------------------------------------------------
__global__ __launch_bounds__(256) void k_gemm(const __bf16* __restrict__ xb,
                                              const __bf16* __restrict__ wmix,
                                              float* __restrict__ xp)
{
  __shared__ __bf16 As[128][72];
  __shared__ __bf16 Bs[128][72];
  const int tid = threadIdx.x, lane = tid & 63, wv = tid >> 6;
  const int quad = lane >> 4, c16 = lane & 15;
  const int wm_ = wv >> 1, wn_ = wv & 1;
  const int b = blockIdx.x >> 5, tile = blockIdx.x & 31;
  const int m0 = (tile >> 4) * 128, n0 = (tile & 15) * 128;
  const __bf16* Ap = xb + (size_t)b * TT * 512;
  const __bf16* Bp = wmix + (size_t)b * 2048 * 512;
  float* Cp = xp + (size_t)b * TT * 2048;

  f32x4 acc[4][4];
  #pragma unroll
  for (int i = 0; i < 4; ++i)
    #pragma unroll
    for (int j = 0; j < 4; ++j) acc[i][j] = (f32x4){0,0,0,0};

  for (int k0 = 0; k0 < 512; k0 += 64){
    __syncthreads();
    #pragma unroll
    for (int it = 0; it < 4; ++it){
      int r = it * 32 + (tid >> 3), c = (tid & 7) * 8;
      *(bf16x8*)&As[r][c] = *(const bf16x8*)(Ap + (size_t)(m0 + r) * 512 + k0 + c);
      *(bf16x8*)&Bs[r][c] = *(const bf16x8*)(Bp + (size_t)(n0 + r) * 512 + k0 + c);
    }
    __syncthreads();
    #pragma unroll
    for (int kt = 0; kt < 2; ++kt){
      bf16x8 af[4], bfr[4];
      #pragma unroll
      for (int i = 0; i < 4; ++i){
        af[i]  = *(const bf16x8*)&As[wm_ * 64 + i * 16 + c16][kt * 32 + quad * 8];
        bfr[i] = *(const bf16x8*)&Bs[wn_ * 64 + i * 16 + c16][kt * 32 + quad * 8];
      }
      #pragma unroll
      for (int i = 0; i < 4; ++i)
        #pragma unroll
        for (int j = 0; j < 4; ++j)
          acc[i][j] = __builtin_amdgcn_mfma_f32_16x16x32_bf16(af[i], bfr[j], acc[i][j], 0, 0, 0);
    }
  }
  #pragma unroll
  for (int i = 0; i < 4; ++i)
    #pragma unroll
    for (int j = 0; j < 4; ++j){
      int colg = n0 + wn_ * 64 + j * 16 + c16;
      #pragma unroll
      for (int r = 0; r < 4; ++r){
        int row = m0 + wm_ * 64 + i * 16 + quad * 4 + r;
        Cp[(size_t)row * 2048 + colg] = acc[i][j][r];
      }
    }
}

// ---------------------------------------------------------------------------
// k_recur R8.
//  Journal (aliases the dead wihm region, write-once per launch):
//    jrn[dir][t][kb=0..63][sample=0..31][16 B]   2 x 256 x 32768 B
//      slot t holds h(t); chunk (kb,sample) = channels kb*8..kb*8+7, bf16.
//      Slot 0 is never read (t=0 uses h==0 in registers); slot t>=1 is
//      written by producers at step t-1 and read (cached) at step t.
//  Counters: cnt[dir][t] u32, zeroed by k_cinit. Producer wg publishes its
//    32 x 8 B slices sc0sc1 -> s_waitcnt vmcnt(0) -> atomic_add(cnt[dir][t+1])
//    (device scope). cnt[dir][t]==128 => all of slot t is MALL-visible.
//  Reader: tid0 polls cnt[dir][t] (sc0sc1 atomic load, 1 word), then
//    __syncthreads, then ALL waves bulk-load slot t with normal cached loads.
//    Journal addresses are never re-read after being re-written inside a
//    launch (write-once), so cached loads cannot be stale; any same-XCD L2
//    fill of a slot-t line happens only after some block observed cnt==128,
//    i.e. after the data was MALL-visible. Cross-launch: dispatch-boundary
//    invalidation + the entry fence below.
//  wg is XCD-swizzled (xproj/out 64B-line locality, kept from R4-R7).
// ---------------------------------------------------------------------------
__global__ __launch_bounds__(256, 1) void k_recur(
    const __bf16* __restrict__ whhp,
    const float*  __restrict__ xproj,   // [2][32][256][2048]
    const float*  __restrict__ biasm,   // [2][32][2048]
    const float*  __restrict__ cb,      // [32][8]
    const int*    __restrict__ lens,    // [32]
    unsigned*     cnt,                  // [2][256] publish counters
    char*         jrn,                  // [2][256][32768] h journal
    float* __restrict__ out)            // [32][256][1024]
{
  // defensive: drop any cross-launch stale L1/L2 lines before first loads
  __builtin_amdgcn_fence(__ATOMIC_ACQUIRE, "agent");

  const int tid = threadIdx.x, lane = tid & 63, wv = tid >> 6;
  const int quad = lane >> 4, c16 = lane & 15;
  const int bid = blockIdx.x, dir = bid >> 7;
  const int b7 = bid & 127;
  const int wg = ((b7 & 7) << 4) | (b7 >> 3);   // XCD-aware swizzle
  const int hidx0 = wg * 4;

  char* jrn_d = jrn + (size_t)dir * 256 * 32768;
  unsigned* cnt_d = cnt + dir * 256;

  // basis-weight B fragments -> registers (logical-wg indexed)
  bf16x8 bfrag[4][8];
  {
    const __bf16* base = whhp + (size_t)((dir * 128 + wg) * 4 + wv) * 4 * (8 * 512);
    #pragma unroll
    for (int kt = 0; kt < 4; ++kt)
      #pragma unroll
      for (int n = 0; n < 8; ++n)
        bfrag[kt][n] = *(const bf16x8*)(base + (size_t)(kt * 8 + n) * 512 + lane * 8);
  }
  f32x4 ccv[2][8];
  #pragma unroll
  for (int mt = 0; mt < 2; ++mt)
    #pragma unroll
    for (int n = 0; n < 8; ++n){
      f32x4 v;
      #pragma unroll
      for (int r = 0; r < 4; ++r) v[r] = cb[(mt * 16 + quad * 4 + r) * 8 + n];
      ccv[mt][n] = v;
    }

  const int bb_ = tid >> 2, jj_ = tid & 3;
  float bias_g[4] = {0, 0, 0, 0};
  int mylen = 0;
  float cstate = 0.f;
  if (tid < 128){
    #pragma unroll
    for (int g = 0; g < 4; ++g)
      bias_g[g] = biasm[(size_t)(dir * 32 + bb_) * 2048 + g * 512 + hidx0 + jj_];
    mylen = lens[bb_];
  }

  __shared__ float red[4][2][64][4];
  __shared__ float xg[32][4][4];
  __shared__ float outst[32][4];
  __shared__ __bf16 hbst[32][4];

  // prefetch xproj for step 0 (normal cached load; waves 0-1)
  f32x4 pf = {0, 0, 0, 0};
  const int b_pf = tid >> 2, g_pf = tid & 3;
  if (tid < 128){
    int to0 = dir ? (TT - 1) : 0;
    pf = *(const f32x4*)(xproj + ((size_t)(dir * 32 + b_pf) * TT + to0) * 2048
                         + g_pf * 512 + hidx0);
  }

  // per-lane chunk indices of the 8 bulk-load chunks (p = mt*4 + kt):
  //   kb = (wv*4+kt)*4 + quad, sample = mt*16 + c16  ->  channels
  //   (wv*4+kt)*32 + quad*8 .. +8 (same fragment map as R5-R7)
  int hidx[8];
  #pragma unroll
  for (int mt = 0; mt < 2; ++mt)
    #pragma unroll
    for (int kt = 0; kt < 4; ++kt)
      hidx[mt * 4 + kt] = (((wv * 4 + kt) * 4 + quad) * 32) + mt * 16 + c16;

  // producer store offset (wave 3, lane s = tid-192): channels wg*4..+3 of
  // sample s live at chunk (wg>>1, s), byte (wg&1)*8 inside it.
  const int pub_off = (((wg >> 1) * 32 + (tid - 192)) << 4) + ((wg & 1) << 3);

  for (int t = 0; t < TT; ++t){
    const int to = dir ? (TT - 1 - t) : t;

    bf16x8 af[2][4];
    if (t == 0){
      // h(0) == 0: no journal slot, no poll
      #pragma unroll
      for (int p = 0; p < 8; ++p)
        af[p >> 2][p & 3] = (bf16x8)(__bf16)0.0f;
      __syncthreads();   // S1 (uniform with t>0 path)
    } else {
      // ---- tid0: poll the single publish counter until all 128 wgs done
      if (tid == 0){
        while (__hip_atomic_load(&cnt_d[t], __ATOMIC_RELAXED,
                                 __HIP_MEMORY_SCOPE_AGENT) < 128u)
          ;
      }
      __syncthreads();   // S1: counter passed -> slot t is MALL-visible

      // ---- bulk-load this wave's quarter of slot t (cached, once) ----
      const u32x4* hb = (const u32x4*)(jrn_d + (size_t)t * 32768);
      u32x4 hv[8];
      #pragma unroll
      for (int p = 0; p < 8; ++p)
        hv[p] = hb[hidx[p]];
      #pragma unroll
      for (int p = 0; p < 8; ++p)
        af[p >> 2][p & 3] = __builtin_bit_cast(bf16x8, hv[p]);
    }

    f32x4 acc[8][2];
    #pragma unroll
    for (int n = 0; n < 8; ++n){ acc[n][0] = (f32x4){0,0,0,0}; acc[n][1] = (f32x4){0,0,0,0}; }
    #pragma unroll
    for (int kt = 0; kt < 4; ++kt)
      #pragma unroll
      for (int n = 0; n < 8; ++n){
        acc[n][0] = __builtin_amdgcn_mfma_f32_16x16x32_bf16(af[0][kt], bfrag[kt][n], acc[n][0], 0, 0, 0);
        acc[n][1] = __builtin_amdgcn_mfma_f32_16x16x32_bf16(af[1][kt], bfrag[kt][n], acc[n][1], 0, 0, 0);
      }
    f32x4 mix0 = {0,0,0,0}, mix1 = {0,0,0,0};
    #pragma unroll
    for (int n = 0; n < 8; ++n){
      mix0 += ccv[0][n] * acc[n][0];
      mix1 += ccv[1][n] * acc[n][1];
    }
    *(f32x4*)&red[wv][0][lane][0] = mix0;
    *(f32x4*)&red[wv][1][lane][0] = mix1;
    if (tid < 128)
      *(f32x4*)&xg[b_pf][g_pf][0] = pf;
    __syncthreads();     // S2

    if (tid < 128){
      const int r = bb_ & 15, mt = bb_ >> 4, rg = r & 3, qp = r >> 2;
      float gv[4];
      #pragma unroll
      for (int g = 0; g < 4; ++g){
        int li = qp * 16 + g * 4 + jj_;
        float s = red[0][mt][li][rg] + red[1][mt][li][rg]
                + red[2][mt][li][rg] + red[3][mt][li][rg];
        gv[g] = s + xg[bb_][g][jj_] + bias_g[g];
      }
      float i_ = sigm(gv[0]);
      float f_ = sigm(gv[1]);
      float g_ = tanh_(gv[2]);
      float o_ = sigm(gv[3]);
      bool valid = (to < mylen);
      float cy = valid ? (f_ * cstate + i_ * g_) : 0.f;
      float hy = valid ? (o_ * tanh_(cy)) : 0.f;
      cstate = cy;
      outst[bb_][jj_] = hy;
      hbst[bb_][jj_] = f2bf(hy);
    }
    __syncthreads();     // S3

    // wave 3: publish h(t+1) slices into slot t+1 (sc0sc1), drain, count
    if (t < TT - 1 && tid >= 192 && tid < 224){
      int s = tid - 192;
      union { bf16x4 h; u32x2 d; } u;
      u.h = *(bf16x4*)&hbst[s][0];
      char* hn = jrn_d + (size_t)(t + 1) * 32768;
      st_b64_coh(hn + pub_off, u.d);
      asm volatile("s_waitcnt vmcnt(0)" ::: "memory");
      if (s == 0)
        __hip_atomic_fetch_add(&cnt_d[t + 1], 1u, __ATOMIC_RELAXED,
                               __HIP_MEMORY_SCOPE_AGENT);
    }
    // waves 0-1: prefetch next xproj (cached); wave 2: out store
    if (t < TT - 1 && tid < 128){
      int ton = dir ? (TT - 2 - t) : (t + 1);
      pf = *(const f32x4*)(xproj + ((size_t)(dir * 32 + b_pf) * TT + ton) * 2048
                           + g_pf * 512 + hidx0);
    }
    if (tid >= 128 && tid < 160){
      int s = tid - 128;
      *(f32x4*)(out + ((size_t)s * TT + to) * 1024 + dir * 512 + hidx0)
          = *(f32x4*)&outst[s][0];
    }
  }
}

// ---------------------------------------------------------------------------
extern "C" void kernel_launch(void* const* d_in, const int* in_sizes, int n_in,
                              void* d_out, int out_size, void* d_ws, size_t ws_size,
                              hipStream_t stream)
{
  const float* x      = (const float*)d_in[0];
  const void*  mask   = d_in[1];
  const int*   meta_a = (const int*)d_in[2];
  const int*   meta_c = (const int*)d_in[3];
  const float* emb_a  = (const float*)d_in[4];
  const float* emb_c  = (const float*)d_in[5];
  const float* P_W1   = (const float*)d_in[6];
  const float* P_b1   = (const float*)d_in[7];
  const float* P_W2   = (const float*)d_in[8];
  const float* W_ih   = (const float*)d_in[9];
  const float* W_hh   = (const float*)d_in[10];
  const float* bias_f = (const float*)d_in[11];
  const float* W_ih_r = (const float*)d_in[12];
  const float* W_hh_r = (const float*)d_in[13];
  const float* bias_r = (const float*)d_in[14];
  float* out = (float*)d_out;
  char* ws = (char*)d_ws;

  constexpr size_t OFF_C     = 0;           //   1 KB  c_batch
  constexpr size_t OFF_LEN   = 1024;        //  128 B  lengths
  constexpr size_t OFF_BIAS  = 4096;        //  512 KB mixed biases
  constexpr size_t OFF_CNT   = 528384;      //   2 KB  publish counters
  constexpr size_t OFF_WHHP  = 790528;      // 33.5 MB basis Whh fragments
  constexpr size_t OFF_XBF   = 34344960;    //  8.4 MB x bf16
  constexpr size_t OFF_WIHM  = 42733568;    //   67 MB mixed Wih (per-dir reuse;
                                            //         journal aliases this
                                            //         region after k_gemm)
  constexpr size_t OFF_XPROJ = 109842432;   //  134 MB xproj f32 (both dirs)
  constexpr size_t WS_NEED   = 244060160;
  if (ws_size < WS_NEED) return;

  float*    c_b   = (float*)(ws + OFF_C);
  int*      lens  = (int*)(ws + OFF_LEN);
  float*    biasm = (float*)(ws + OFF_BIAS);
  unsigned* cnt   = (unsigned*)(ws + OFF_CNT);
  __bf16*   whhp  = (__bf16*)(ws + OFF_WHHP);
  __bf16*   xbf   = (__bf16*)(ws + OFF_XBF);
  __bf16*   wihm  = (__bf16*)(ws + OFF_WIHM);
  char*     jrn   = (char*)(ws + OFF_WIHM);  // 16.8 MB, dead wihm space
  float*    xproj = (float*)(ws + OFF_XPROJ);

  k_meta<<<1, 256, 0, stream>>>(mask, meta_a, meta_c, emb_a, emb_c,
                                P_W1, P_b1, P_W2, c_b, lens);
  k_cinit<<<2, 256, 0, stream>>>(cnt);
  k_xbf<<<2048, 256, 0, stream>>>(x, xbf);
  k_whhp<<<8192, 256, 0, stream>>>(W_hh, W_hh_r, whhp);
  k_bias<<<512, 256, 0, stream>>>(bias_f, bias_r, c_b, biasm);
  for (int dir = 0; dir < 2; ++dir){
    k_mixwih<<<512, 256, 0, stream>>>(dir ? W_ih_r : W_ih, c_b, wihm);
    k_gemm<<<1024, 256, 0, stream>>>(xbf, wihm,
                                     xproj + (size_t)dir * 32 * TT * 2048);
  }
  k_recur<<<256, 256, 0, stream>>>(whhp, xproj, biasm, c_b, lens, cnt, jrn, out);
}

// Round 4
// 1685.945 us; speedup vs baseline: 1.2078x; 1.1799x over previous
//
#include <hip/hip_runtime.h>
#include <hip/hip_bf16.h>
#include <stdint.h>

// ---------------------------------------------------------------------------
// BasisCustBiLSTM: per-sample basis-mixed BiLSTM.
//   k_meta / k_xbf / k_whhp / k_bias / k_mixwih / k_gemm : prep (unchanged)
//   k_recur R9: dual-chain latency hiding.
//     R5-R8 lessons: per-step cost = D + W, with W ~1 us of work and
//     D ~4.5 us of irreducible publish->visible->detect->fetch MALL latency
//     (R6/R7/R8 each attacked D's bandwidth/caching/width and all failed;
//     only added RTs ever moved the number). R9 HIDES D instead: the 32
//     samples are independent recurrences, so split them into chain A
//     (samples 0-15) and chain B (16-31), interleaved as two phases per
//     iteration, each with its own R5-style fused tagged records
//     ({4x bf16 h, tag} 16 B, one sc0sc1 store, no drain, no flags).
//     While chain A's publish propagates, chain B computes, and vice versa;
//     steady state period = D + W covering TWO steps -> ~2x.
//     The mt in {0,1} accumulator-tile dimension of R5 is promoted to the
//     phase index: all lane->sample, record->channel, C/D maps unchanged.
//     Per-chain init / overwrite-safety arguments identical to R5.
// ---------------------------------------------------------------------------

typedef __attribute__((ext_vector_type(8))) __bf16 bf16x8;
typedef __attribute__((ext_vector_type(4))) __bf16 bf16x4;
typedef __attribute__((ext_vector_type(4))) float  f32x4;
typedef __attribute__((ext_vector_type(4))) unsigned u32x4;
typedef __attribute__((ext_vector_type(2))) unsigned u32x2;

#define TT 256
#define BBATCH 32

__device__ __forceinline__ __bf16 f2bf(float f){
  unsigned u = __builtin_bit_cast(unsigned, f);
  unsigned short r = (unsigned short)((u + 0x7fffu + ((u >> 16) & 1u)) >> 16);
  return __builtin_bit_cast(__bf16, r);
}
__device__ __forceinline__ float sigm(float x){
  x = fminf(fmaxf(x, -30.f), 30.f);
  return 1.f / (1.f + __expf(-x));
}
__device__ __forceinline__ float tanh_(float x){
  x = fminf(fmaxf(x, -15.f), 15.f);
  float e = __expf(2.f * x);
  return (e - 1.f) / (e + 1.f);
}

// --- coherent (MALL-level) access helpers: sc0 sc1 = bypass L1+L2 ----------
__device__ __forceinline__ u32x4 ld_b128_coh(const void* p){
  u32x4 v;
  asm volatile("global_load_dwordx4 %0, %1, off sc0 sc1"
               : "=v"(v) : "v"(p) : "memory");
  return v;
}
__device__ __forceinline__ void st_b128_coh(void* p, u32x4 v){
  asm volatile("global_store_dwordx4 %0, %1, off sc0 sc1"
               :: "v"(p), "v"(v) : "memory");
}

// ---------------------------------------------------------------------------
__global__ void k_meta(const void* __restrict__ mask,
                       const int* __restrict__ meta_a, const int* __restrict__ meta_c,
                       const float* __restrict__ emb_a, const float* __restrict__ emb_c,
                       const float* __restrict__ W1, const float* __restrict__ b1,
                       const float* __restrict__ W2,
                       float* __restrict__ c_out, int* __restrict__ len_out)
{
  __shared__ int s_bad;
  __shared__ float q_sh[32][128];
  __shared__ float hid[32][64];
  const int tid = threadIdx.x;
  if (tid == 0) s_bad = 0;
  __syncthreads();

  if (tid < 32){
    const unsigned char* m8 = (const unsigned char*)mask;
    int cnt = 0, seen0 = 0, bad = 0;
    for (int t = 0; t < TT; ++t){
      unsigned char v = m8[tid * TT + t];
      if (v > 1) bad = 1;
      if (v){ if (seen0) bad = 1; cnt++; } else seen0 = 1;
    }
    if (tid == 0 && cnt != TT) bad = 1;
    if (bad) atomicAdd(&s_bad, 1);
    len_out[tid] = cnt;
  }
  {
    int b = tid >> 3, p = tid & 7;
    int a = meta_a[b], c = meta_c[b];
    for (int i = 0; i < 16; ++i){
      int qi = p * 16 + i;
      q_sh[b][qi] = (qi < 64) ? emb_a[a * 64 + qi] : emb_c[c * 64 + (qi - 64)];
    }
  }
  __syncthreads();
  if (s_bad){
    if (tid < 32){
      const int* m32 = (const int*)mask;
      int cnt = 0;
      for (int t = 0; t < TT; ++t) if (m32[tid * TT + t]) cnt++;
      len_out[tid] = cnt;
    }
  }
  {
    int b = tid >> 3, kg = tid & 7;
    for (int k8 = 0; k8 < 8; ++k8){
      int k = kg * 8 + k8;
      float s = b1[k];
      for (int i = 0; i < 128; ++i) s += q_sh[b][i] * W1[i * 64 + k];
      hid[b][k] = tanhf(s);
    }
  }
  __syncthreads();
  if (tid < 32){
    float lg[8]; float mx = -1e30f;
    for (int n = 0; n < 8; ++n){
      float s = 0.f;
      for (int k = 0; k < 64; ++k) s += hid[tid][k] * W2[k * 8 + n];
      lg[n] = s; mx = fmaxf(mx, s);
    }
    float den = 0.f;
    for (int n = 0; n < 8; ++n){ lg[n] = expf(lg[n] - mx); den += lg[n]; }
    for (int n = 0; n < 8; ++n) c_out[tid * 8 + n] = lg[n] / den;
  }
}

// ---------------------------------------------------------------------------
__global__ void k_xbf(const float* __restrict__ x, __bf16* __restrict__ xb)
{
  int i = blockIdx.x * 256 + threadIdx.x;
  if (i >= 524288) return;
  f32x4 a = *(const f32x4*)(x + (size_t)i * 8);
  f32x4 b = *(const f32x4*)(x + (size_t)i * 8 + 4);
  bf16x8 o;
  #pragma unroll
  for (int j = 0; j < 4; ++j){ o[j] = f2bf(a[j]); o[4 + j] = f2bf(b[j]); }
  *(bf16x8*)(xb + (size_t)i * 8) = o;
}

// ---------------------------------------------------------------------------
__global__ void k_whhp(const float* __restrict__ whh_f, const float* __restrict__ whh_r,
                       __bf16* __restrict__ outp)
{
  int idx = blockIdx.x * 256 + threadIdx.x;
  int lane = idx & 63; int grp = idx >> 6;
  int n  = grp & 7;  grp >>= 3;
  int kt = grp & 3;  grp >>= 2;
  int wv = grp & 3;  grp >>= 2;
  int wg = grp & 127; int dir = (grp >> 7) & 1;
  int col = lane & 15, quad = lane >> 4;
  int gate = col >> 2, jj = col & 3;
  int g = gate * 512 + wg * 4 + jj;
  int k = (wv * 4 + kt) * 32 + quad * 8;
  const float* Wb = dir ? whh_r : whh_f;
  const float* s = Wb + ((size_t)n * 2048 + g) * 512 + k;
  f32x4 a = *(const f32x4*)s, b = *(const f32x4*)(s + 4);
  bf16x8 o;
  #pragma unroll
  for (int j = 0; j < 4; ++j){ o[j] = f2bf(a[j]); o[4 + j] = f2bf(b[j]); }
  *(bf16x8*)(outp + (size_t)idx * 8) = o;
}

// ---------------------------------------------------------------------------
__global__ void k_bias(const float* __restrict__ b_f, const float* __restrict__ b_r,
                       const float* __restrict__ cb, float* __restrict__ bm)
{
  int idx = blockIdx.x * 256 + threadIdx.x;
  int dir = idx >> 16; int b = (idx >> 11) & 31; int g = idx & 2047;
  const float* bb = dir ? b_r : b_f;
  float s = 0.f;
  #pragma unroll
  for (int n = 0; n < 8; ++n) s += cb[b * 8 + n] * bb[n * 2048 + g];
  bm[idx] = s;
}

// ---------------------------------------------------------------------------
__global__ void k_mixwih(const float* __restrict__ Wb, const float* __restrict__ cb,
                         __bf16* __restrict__ wmix)
{
  __shared__ float cs[256];
  int tid = threadIdx.x;
  cs[tid] = cb[tid];
  __syncthreads();
  int idx = blockIdx.x * 256 + tid;
  int g = idx >> 6, k8 = idx & 63;
  float src[8][8];
  #pragma unroll
  for (int n = 0; n < 8; ++n){
    const float* p = Wb + ((size_t)n * 2048 + g) * 512 + k8 * 8;
    f32x4 lo = *(const f32x4*)p, hi = *(const f32x4*)(p + 4);
    #pragma unroll
    for (int j = 0; j < 4; ++j){ src[n][j] = lo[j]; src[n][4 + j] = hi[j]; }
  }
  for (int b = 0; b < 32; ++b){
    float acc[8] = {0,0,0,0,0,0,0,0};
    #pragma unroll
    for (int n = 0; n < 8; ++n){
      float cn = cs[b * 8 + n];
      #pragma unroll
      for (int j = 0; j < 8; ++j) acc[j] += cn * src[n][j];
    }
    bf16x8 o;
    #pragma unroll
    for (int j = 0; j < 8; ++j) o[j] = f2bf(acc[j]);
    *(bf16x8*)(wmix + ((size_t)b * 2048 + g) * 512 + k8 * 8) = o;
  }
}

// ---------------------------------------------------------------------------
__global__ __launch_bounds__(256) void k_gemm(const __bf16* __restrict__ xb,
                                              const __bf16* __restrict__ wmix,
                                              float* __restrict__ xp)
{
  __shared__ __bf16 As[128][72];
  __shared__ __bf16 Bs[128][72];
  const int tid = threadIdx.x, lane = tid & 63, wv = tid >> 6;
  const int quad = lane >> 4, c16 = lane & 15;
  const int wm_ = wv >> 1, wn_ = wv & 1;
  const int b = blockIdx.x >> 5, tile = blockIdx.x & 31;
  const int m0 = (tile >> 4) * 128, n0 = (tile & 15) * 128;
  const __bf16* Ap = xb + (size_t)b * TT * 512;
  const __bf16* Bp = wmix + (size_t)b * 2048 * 512;
  float* Cp = xp + (size_t)b * TT * 2048;

  f32x4 acc[4][4];
  #pragma unroll
  for (int i = 0; i < 4; ++i)
    #pragma unroll
    for (int j = 0; j < 4; ++j) acc[i][j] = (f32x4){0,0,0,0};

  for (int k0 = 0; k0 < 512; k0 += 64){
    __syncthreads();
    #pragma unroll
    for (int it = 0; it < 4; ++it){
      int r = it * 32 + (tid >> 3), c = (tid & 7) * 8;
      *(bf16x8*)&As[r][c] = *(const bf16x8*)(Ap + (size_t)(m0 + r) * 512 + k0 + c);
      *(bf16x8*)&Bs[r][c] = *(const bf16x8*)(Bp + (size_t)(n0 + r) * 512 + k0 + c);
    }
    __syncthreads();
    #pragma unroll
    for (int kt = 0; kt < 2; ++kt){
      bf16x8 af[4], bfr[4];
      #pragma unroll
      for (int i = 0; i < 4; ++i){
        af[i]  = *(const bf16x8*)&As[wm_ * 64 + i * 16 + c16][kt * 32 + quad * 8];
        bfr[i] = *(const bf16x8*)&Bs[wn_ * 64 + i * 16 + c16][kt * 32 + quad * 8];
      }
      #pragma unroll
      for (int i = 0; i < 4; ++i)
        #pragma unroll
        for (int j = 0; j < 4; ++j)
          acc[i][j] = __builtin_amdgcn_mfma_f32_16x16x32_bf16(af[i], bfr[j], acc[i][j], 0, 0, 0);
    }
  }
  #pragma unroll
  for (int i = 0; i < 4; ++i)
    #pragma unroll
    for (int j = 0; j < 4; ++j){
      int colg = n0 + wn_ * 64 + j * 16 + c16;
      #pragma unroll
      for (int r = 0; r < 4; ++r){
        int row = m0 + wm_ * 64 + i * 16 + quad * 4 + r;
        Cp[(size_t)row * 2048 + colg] = acc[i][j][r];
      }
    }
}

// ---------------------------------------------------------------------------
// k_recur R9. Record buffers (256 KB total, at OFF_H):
//   rec[dir][chain g][buf][sample s 0..15][wg 0..127] = {h01, h23, tag, 0}
//     16 B; base offset ((dir*2+g)*2+buf) << 15.
//   chain g covers global samples g*16 .. g*16+15; records carry channels
//   wg*4..wg*4+3 of one sample.
// Protocol per chain (exactly R5's): buf[t&1] with tag==t is the h input of
//   step t. Each block writes tag-0 zero records into buf0 for its wg at
//   start; publishes tag t+1 into buf[(t+1)&1] after the cell of step t
//   (ONE fused store, no drain, no flag). Readers poll their own fragment
//   records until all tags == t. Launch-safety: stale tags from a previous
//   launch are >=1, never falsely ==0 before the fresh init lands; records
//   are 2-step periodic so equality-poll has no false positives.
// Overwrite safety per chain: a block publishes tag t+2 into buf[t&1] only
//   after passing its chain-g step-t+1 poll, which requires every block to
//   have published t+1, which requires their step-t reads completed.
// Iteration = phase A (chain 0) then phase B (chain 1): while A's publish
//   propagates (D ~4.5 us), B computes, and vice versa -> period D+W per
//   TWO steps.
// wg is XCD-swizzled (xproj/out 64B-line locality).
// ---------------------------------------------------------------------------
__global__ __launch_bounds__(256, 1) void k_recur(
    const __bf16* __restrict__ whhp,
    const float*  __restrict__ xproj,   // [2][32][256][2048]
    const float*  __restrict__ biasm,   // [2][32][2048]
    const float*  __restrict__ cb,      // [32][8]
    const int*    __restrict__ lens,    // [32]
    char* hrec,                         // record region (see above)
    float* __restrict__ out)            // [32][256][1024]
{
  const int tid = threadIdx.x, lane = tid & 63, wv = tid >> 6;
  const int quad = lane >> 4, c16 = lane & 15;
  const int bid = blockIdx.x, dir = bid >> 7;
  const int b7 = bid & 127;
  const int wg = ((b7 & 7) << 4) | (b7 >> 3);   // XCD-aware swizzle
  const int hidx0 = wg * 4;

  // basis-weight B fragments -> registers (logical-wg indexed)
  bf16x8 bfrag[4][8];
  {
    const __bf16* base = whhp + (size_t)((dir * 128 + wg) * 4 + wv) * 4 * (8 * 512);
    #pragma unroll
    for (int kt = 0; kt < 4; ++kt)
      #pragma unroll
      for (int n = 0; n < 8; ++n)
        bfrag[kt][n] = *(const bf16x8*)(base + (size_t)(kt * 8 + n) * 512 + lane * 8);
  }
  // c_batch columns for this lane's accumulator rows, per chain
  f32x4 ccv[2][8];
  #pragma unroll
  for (int g = 0; g < 2; ++g)
    #pragma unroll
    for (int n = 0; n < 8; ++n){
      f32x4 v;
      #pragma unroll
      for (int r = 0; r < 4; ++r) v[r] = cb[(g * 16 + quad * 4 + r) * 8 + n];
      ccv[g][n] = v;
    }

  // cell-thread state (tid < 64): sample s_ within chain, channel jj2
  const int s_ = tid >> 2, jj2 = tid & 3;
  float bias_gc[2][4] = {{0,0,0,0},{0,0,0,0}};
  int   mylen[2] = {0, 0};
  float cst[2] = {0.f, 0.f};
  if (tid < 64){
    #pragma unroll
    for (int g = 0; g < 2; ++g){
      #pragma unroll
      for (int gg = 0; gg < 4; ++gg)
        bias_gc[g][gg] = biasm[(size_t)(dir * 32 + g * 16 + s_) * 2048
                               + gg * 512 + hidx0 + jj2];
      mylen[g] = lens[g * 16 + s_];
    }
  }

  __shared__ float red[4][64][4];
  __shared__ float xg[32][4][4];
  __shared__ float outst[16][4];
  __shared__ __bf16 hbst[16][4];

  // init: lanes 192..223 publish zero-records (tag 0) into buf0, both chains
  if (tid >= 192 && tid < 224){
    int i = tid - 192, gi = i >> 4, sg = i & 15;
    u32x4 z = {0u, 0u, 0u, 0u};
    u32x4* wb = (u32x4*)(hrec + (((size_t)(dir * 2 + gi) * 2 + 0) << 15));
    st_b128_coh(wb + sg * 128 + wg, z);
  }

  // prefetch xproj for step 0 (normal cached load; waves 0-1)
  f32x4 pf = {0, 0, 0, 0};
  const int b_pf = tid >> 2, g_pf = tid & 3;
  if (tid < 128){
    int to0 = dir ? (TT - 1) : 0;
    pf = *(const f32x4*)(xproj + ((size_t)(dir * 32 + b_pf) * TT + to0) * 2048
                         + g_pf * 512 + hidx0);
  }

  // per-lane record indices (units of 16 B records), per kt: sample = c16,
  // channels (wv*4+kt)*32 + quad*8 .. +8 = records (wg0, wg0+1)
  int ridx[4];
  #pragma unroll
  for (int kt = 0; kt < 4; ++kt)
    ridx[kt] = c16 * 128 + (wv * 4 + kt) * 8 + quad * 2;

  for (int t = 0; t < TT; ++t){
    const int to = dir ? (TT - 1 - t) : t;
    const unsigned tgt = (unsigned)t;

    #pragma unroll
    for (int g = 0; g < 2; ++g){
      const u32x4* rb = (const u32x4*)(hrec
                        + (((size_t)(dir * 2 + g) * 2 + (t & 1)) << 15));

      // ---- poll-load this wave's fragment records until all tags == t ----
      u32x4 r0[4], r1[4];
      while (true){
        #pragma unroll
        for (int p = 0; p < 4; ++p){
          r0[p] = ld_b128_coh(rb + ridx[p]);
          r1[p] = ld_b128_coh(rb + ridx[p] + 1);
        }
        asm volatile("s_waitcnt vmcnt(0)"
                     : "+v"(r0[0]), "+v"(r0[1]), "+v"(r0[2]), "+v"(r0[3]),
                       "+v"(r1[0]), "+v"(r1[1]), "+v"(r1[2]), "+v"(r1[3])
                     :: "memory");
        unsigned bad = 0;
        #pragma unroll
        for (int p = 0; p < 4; ++p)
          bad |= (r0[p][2] ^ tgt) | (r1[p][2] ^ tgt);
        if (__all((int)(bad == 0u))) break;
      }
      bf16x8 af[4];
      #pragma unroll
      for (int p = 0; p < 4; ++p){
        u32x4 w = {r0[p][0], r0[p][1], r1[p][0], r1[p][1]};
        af[p] = __builtin_bit_cast(bf16x8, w);
      }

      // ---- MFMA: h(16 samples) x basis weights, mix over basis ----
      f32x4 acc[8];
      #pragma unroll
      for (int n = 0; n < 8; ++n) acc[n] = (f32x4){0,0,0,0};
      #pragma unroll
      for (int kt = 0; kt < 4; ++kt)
        #pragma unroll
        for (int n = 0; n < 8; ++n)
          acc[n] = __builtin_amdgcn_mfma_f32_16x16x32_bf16(af[kt], bfrag[kt][n], acc[n], 0, 0, 0);
      f32x4 mix = {0,0,0,0};
      #pragma unroll
      for (int n = 0; n < 8; ++n) mix += ccv[g][n] * acc[n];
      *(f32x4*)&red[wv][lane][0] = mix;
      if (g == 0 && tid < 128)
        *(f32x4*)&xg[b_pf][g_pf][0] = pf;   // xproj for ALL 32 samples, step t
      __syncthreads();   // S2: red/xg ready

      // ---- cell (tid<64): 16 samples x 4 channels of this chain ----
      if (tid < 64){
        const int qp = s_ >> 2, rg = s_ & 3;
        float gv[4];
        #pragma unroll
        for (int gg = 0; gg < 4; ++gg){
          int li = qp * 16 + gg * 4 + jj2;
          float s = red[0][li][rg] + red[1][li][rg]
                  + red[2][li][rg] + red[3][li][rg];
          gv[gg] = s + xg[g * 16 + s_][gg][jj2] + bias_gc[g][gg];
        }
        float i_ = sigm(gv[0]);
        float f_ = sigm(gv[1]);
        float g_ = tanh_(gv[2]);
        float o_ = sigm(gv[3]);
        bool valid = (to < mylen[g]);
        float cy = valid ? (f_ * cst[g] + i_ * g_) : 0.f;
        float hy = valid ? (o_ * tanh_(cy)) : 0.f;
        cst[g] = cy;
        outst[s_][jj2] = hy;
        hbst[s_][jj2] = f2bf(hy);
      }
      __syncthreads();   // S3: outst/hbst ready

      // ---- publish tagged records for step t+1 (fused, fire-and-forget) --
      if (tid >= 192 && tid < 208){
        int sg = tid - 192;
        union { bf16x4 h; u32x2 d; } u;
        u.h = *(bf16x4*)&hbst[sg][0];
        u32x4 rec = {u.d[0], u.d[1], (unsigned)(t + 1), 0u};
        u32x4* wb = (u32x4*)(hrec
                    + (((size_t)(dir * 2 + g) * 2 + ((t + 1) & 1)) << 15));
        st_b128_coh(wb + sg * 128 + wg, rec);
      }
      // ---- out store for this chain's 16 samples ----
      if (tid >= 128 && tid < 144){
        int sg = tid - 128;
        *(f32x4*)(out + ((size_t)(g * 16 + sg) * TT + to) * 1024
                  + dir * 512 + hidx0)
            = *(f32x4*)&outst[sg][0];
      }
      // ---- end of phase B: prefetch next step's xproj (cached) ----
      if (g == 1 && t < TT - 1 && tid < 128){
        int ton = dir ? (TT - 2 - t) : (t + 1);
        pf = *(const f32x4*)(xproj + ((size_t)(dir * 32 + b_pf) * TT + ton) * 2048
                             + g_pf * 512 + hidx0);
      }
    }
  }
}

// ---------------------------------------------------------------------------
extern "C" void kernel_launch(void* const* d_in, const int* in_sizes, int n_in,
                              void* d_out, int out_size, void* d_ws, size_t ws_size,
                              hipStream_t stream)
{
  const float* x      = (const float*)d_in[0];
  const void*  mask   = d_in[1];
  const int*   meta_a = (const int*)d_in[2];
  const int*   meta_c = (const int*)d_in[3];
  const float* emb_a  = (const float*)d_in[4];
  const float* emb_c  = (const float*)d_in[5];
  const float* P_W1   = (const float*)d_in[6];
  const float* P_b1   = (const float*)d_in[7];
  const float* P_W2   = (const float*)d_in[8];
  const float* W_ih   = (const float*)d_in[9];
  const float* W_hh   = (const float*)d_in[10];
  const float* bias_f = (const float*)d_in[11];
  const float* W_ih_r = (const float*)d_in[12];
  const float* W_hh_r = (const float*)d_in[13];
  const float* bias_r = (const float*)d_in[14];
  float* out = (float*)d_out;
  char* ws = (char*)d_ws;

  constexpr size_t OFF_C     = 0;           //   1 KB  c_batch
  constexpr size_t OFF_LEN   = 1024;        //  128 B  lengths
  constexpr size_t OFF_BIAS  = 4096;        //  512 KB mixed biases
  constexpr size_t OFF_H     = 528384;      //  256 KB tagged h records (R9)
  constexpr size_t OFF_WHHP  = 790528;      // 33.5 MB basis Whh fragments
  constexpr size_t OFF_XBF   = 34344960;    //  8.4 MB x bf16
  constexpr size_t OFF_WIHM  = 42733568;    //   67 MB mixed Wih (per-dir reuse)
  constexpr size_t OFF_XPROJ = 109842432;   //  134 MB xproj f32 (both dirs)
  constexpr size_t WS_NEED   = 244060160;
  if (ws_size < WS_NEED) return;

  float*   c_b   = (float*)(ws + OFF_C);
  int*     lens  = (int*)(ws + OFF_LEN);
  float*   biasm = (float*)(ws + OFF_BIAS);
  char*    hrec  = (char*)(ws + OFF_H);
  __bf16*  whhp  = (__bf16*)(ws + OFF_WHHP);
  __bf16*  xbf   = (__bf16*)(ws + OFF_XBF);
  __bf16*  wihm  = (__bf16*)(ws + OFF_WIHM);
  float*   xproj = (float*)(ws + OFF_XPROJ);

  k_meta<<<1, 256, 0, stream>>>(mask, meta_a, meta_c, emb_a, emb_c,
                                P_W1, P_b1, P_W2, c_b, lens);
  k_xbf<<<2048, 256, 0, stream>>>(x, xbf);
  k_whhp<<<8192, 256, 0, stream>>>(W_hh, W_hh_r, whhp);
  k_bias<<<512, 256, 0, stream>>>(bias_f, bias_r, c_b, biasm);
  for (int dir = 0; dir < 2; ++dir){
    k_mixwih<<<512, 256, 0, stream>>>(dir ? W_ih_r : W_ih, c_b, wihm);
    k_gemm<<<1024, 256, 0, stream>>>(xbf, wihm,
                                     xproj + (size_t)dir * 32 * TT * 2048);
  }
  k_recur<<<256, 256, 0, stream>>>(whhp, xproj, biasm, c_b, lens, hrec, out);
}